// Round 7
// baseline (378.217 us; speedup 1.0000x reference)
//
#include <hip/hip_runtime.h>

// GAT (3-layer) on MI355X. N=50000 nodes, E=800000 edges, D=64, H=2/2/1.
// R7: scatter 4-edge/thread + uint16 ssrc (R6: returning-atomic chain + 4B
//     scatter writeback made it 50us); agg pass-2 16-deep; embed fused into
//     gemm0; single wprep. 13 dispatches.

typedef __attribute__((ext_vector_type(8))) short short8;   // 8 bf16 (4 VGPRs)
typedef __attribute__((ext_vector_type(4))) float float4v;  // 4 fp32 acc

__device__ __forceinline__ float lrelu(float x){ return x >= 0.f ? x : 0.2f*x; }

__device__ __forceinline__ unsigned short f2bf(float f){   // RNE round
  unsigned int u = __float_as_uint(f);
  u += 0x7fffu + ((u >> 16) & 1u);
  return (unsigned short)(u >> 16);
}
__device__ __forceinline__ float bf2f(unsigned short u){
  return __uint_as_float((unsigned int)u << 16);
}
__device__ __forceinline__ float rl_f(float v, int l){
  return __int_as_float(__builtin_amdgcn_readlane(__float_as_int(v), l));
}

__global__ void k_zero_i32(int* __restrict__ p, int n){
  int i = blockIdx.x*blockDim.x + threadIdx.x;
  if (i < n) p[i] = 0;
}

__global__ void k_hist(const int* __restrict__ dst, int* __restrict__ counts, int E){
  int i0 = (blockIdx.x*blockDim.x + threadIdx.x)*4;
  #pragma unroll
  for (int u = 0; u < 4; u++){
    int i = i0 + u;
    if (i < E) atomicAdd(&counts[dst[i]], 1);
  }
}

__global__ void k_scan_local(const int* __restrict__ counts, int* __restrict__ row_ptr,
                             int* __restrict__ bsum, int N){
  __shared__ int s[256];
  int t = threadIdx.x, g = blockIdx.x*256 + t;
  int v = (g < N) ? counts[g] : 0;
  s[t] = v; __syncthreads();
  #pragma unroll
  for (int off = 1; off < 256; off <<= 1){
    int x = 0;
    if (t >= off) x = s[t-off];
    __syncthreads();
    s[t] += x;
    __syncthreads();
  }
  if (g < N) row_ptr[g+1] = s[t];
  if (g == 0 && t == 0) row_ptr[0] = 0;
  if (t == 255) bsum[blockIdx.x] = s[255];
}

__global__ void k_scan_top(int* __restrict__ bsum, int nb){
  __shared__ int s[256];
  int t = threadIdx.x;
  int v = (t < nb) ? bsum[t] : 0;
  s[t] = v; __syncthreads();
  #pragma unroll
  for (int off = 1; off < 256; off <<= 1){
    int x = 0;
    if (t >= off) x = s[t-off];
    __syncthreads();
    s[t] += x;
    __syncthreads();
  }
  if (t < nb) bsum[t] = s[t] - v;  // exclusive block offsets
}

__global__ void k_scan_fix(int* __restrict__ row_ptr, const int* __restrict__ bsum, int N){
  int g = blockIdx.x*256 + threadIdx.x;
  if (g < N && blockIdx.x > 0) row_ptr[g+1] += bsum[blockIdx.x];
}

// 4 edges/thread: 4 independent atomic->store chains in flight per lane.
__global__ void k_scatter(const int* __restrict__ src, const int* __restrict__ dst,
                          const int* __restrict__ row_ptr, int* __restrict__ cursor,
                          unsigned short* __restrict__ ssrc, int E){
  int i0 = (blockIdx.x*blockDim.x + threadIdx.x)*4;
  #pragma unroll
  for (int u = 0; u < 4; u++){
    int i = i0 + u;
    if (i < E){
      int d = dst[i];
      int pos = atomicAdd(&cursor[d], 1);
      ssrc[row_ptr[d] + pos] = (unsigned short)src[i];
    }
  }
}

// All three weight transposes (fp32 -> bf16, n-major) in one dispatch.
__global__ void k_wprep_all(const float* __restrict__ W0, const float* __restrict__ W1,
                            const float* __restrict__ W2, const float* __restrict__ rW2,
                            unsigned short* __restrict__ Wt0, unsigned short* __restrict__ Wt1,
                            unsigned short* __restrict__ Wt2){
  int id = blockIdx.x*256 + threadIdx.x;
  if (id < 128*64){
    int n = id/64, k = id%64;
    Wt0[n*64 + k] = f2bf(W0[k*128 + n]);
  } else if (id < 128*64 + 128*128){
    int j = id - 128*64; int n = j/128, k = j%128;
    Wt1[n*128 + k] = f2bf(W1[k*128 + n]);
  } else if (id < 128*64 + 2*128*128){
    int j = id - 128*64 - 128*128; int n = j/128, k = j%128;
    float v = (n < 64) ? W2[k*64 + n] : rW2[k*64 + (n - 64)];
    Wt2[n*128 + k] = f2bf(v);
  }
}

// MFMA GEMM: fhb[N][128](bf16 row-major) = hb[N][IN](bf16) @ W(128 cols via Wt).
// Block 256 thr = 4 waves; wave computes 16 rows x 128 cols (8 accs, IN/32 K-steps).
// Layouts (verified): A[m=lane&15][k=quad*8+j]; B[k=quad*8+j][n=lane&15];
// D: col=lane&15, row=quad*4+reg. el/er fused (16-lane butterfly per quad).
// EMBED: A built from emb[feat[row]]*fv[row] (fp32 global -> bf16 regs).
template<int IN, int H, bool EMBED>
__global__ __launch_bounds__(256) void k_gemm_mfma(
    const unsigned short* __restrict__ hb,   // [N][IN] bf16 (unused if EMBED)
    const int* __restrict__ feat, const float* __restrict__ fv, const float* __restrict__ emb,
    const unsigned short* __restrict__ Wt,   // [128][IN] bf16, n-major
    const float* __restrict__ al, const float* __restrict__ ar,
    unsigned short* __restrict__ fhb,        // [N][128] bf16
    float* __restrict__ elr, int N){
  constexpr int KS = IN/32;
  constexpr int LDP = IN + 8;                // +8 bf16 pad: 2-way bank aliasing = free
  __shared__ unsigned short Wt_s[128*LDP];
  const int t = threadIdx.x;
  const int lane = t & 63, wid = t >> 6;
  const int l15 = lane & 15, quad = lane >> 4;
  const int row0 = blockIdx.x*64 + wid*16;

  // stage Wt -> LDS (uint4 = 8 bf16)
  for (int id = t; id < 128*(IN/8); id += 256){
    int r = id/(IN/8), seg = id%(IN/8);
    ((uint4*)(Wt_s + r*LDP))[seg] = ((const uint4*)(Wt + (size_t)r*IN))[seg];
  }
  // A fragments (overlaps LDS staging)
  short8 a[KS];
  int arow = row0 + l15;
  if (EMBED){
    int f = 0; float sc = 0.f;
    if (arow < N){ f = feat[arow]; sc = fv[arow]; }
    #pragma unroll
    for (int s = 0; s < KS; s++){
      const float* ep = emb + (size_t)f*64 + s*32 + quad*8;
      float4 v0 = ((const float4*)ep)[0];
      float4 v1 = ((const float4*)ep)[1];
      short8 av;
      av[0]=(short)f2bf(v0.x*sc); av[1]=(short)f2bf(v0.y*sc);
      av[2]=(short)f2bf(v0.z*sc); av[3]=(short)f2bf(v0.w*sc);
      av[4]=(short)f2bf(v1.x*sc); av[5]=(short)f2bf(v1.y*sc);
      av[6]=(short)f2bf(v1.z*sc); av[7]=(short)f2bf(v1.w*sc);
      a[s] = av;
    }
  } else {
    #pragma unroll
    for (int s = 0; s < KS; s++){
      if (arow < N) a[s] = *(const short8*)(hb + (size_t)arow*IN + s*32 + quad*8);
      else          a[s] = short8{0,0,0,0,0,0,0,0};
    }
  }
  __syncthreads();

  float4v acc[8];
  #pragma unroll
  for (int nt = 0; nt < 8; nt++) acc[nt] = float4v{0.f,0.f,0.f,0.f};
  #pragma unroll
  for (int nt = 0; nt < 8; nt++){
    #pragma unroll
    for (int s = 0; s < KS; s++){
      short8 b = *(const short8*)(Wt_s + (nt*16 + l15)*LDP + s*32 + quad*8);
      acc[nt] = __builtin_amdgcn_mfma_f32_16x16x32_bf16(a[s], b, acc[nt], 0, 0, 0);
    }
  }

  // al/ar at this lane's columns (col = nt*16 + l15); H==1: heads>0 are zero
  float alc[8], arc[8];
  #pragma unroll
  for (int nt = 0; nt < 8; nt++){
    bool hv = (H == 2) || (nt < 4);
    alc[nt] = hv ? al[nt*16 + l15] : 0.f;
    arc[nt] = hv ? ar[nt*16 + l15] : 0.f;
  }
  #pragma unroll
  for (int reg = 0; reg < 4; reg++){
    int row = row0 + quad*4 + reg;
    bool rv = row < N;
    if (rv){
      #pragma unroll
      for (int nt = 0; nt < 8; nt++)
        fhb[(size_t)row*128 + nt*16 + l15] = f2bf(acc[nt][reg]);
    }
    float pel0 = 0.f, per0 = 0.f, pel1 = 0.f, per1 = 0.f;
    #pragma unroll
    for (int nt = 0; nt < 4; nt++){
      pel0 += acc[nt][reg]*alc[nt];     per0 += acc[nt][reg]*arc[nt];
      pel1 += acc[nt+4][reg]*alc[nt+4]; per1 += acc[nt+4][reg]*arc[nt+4];
    }
    #pragma unroll
    for (int off = 1; off < 16; off <<= 1){   // reduce across the 16 lanes of a quad
      pel0 += __shfl_xor(pel0, off, 64);
      pel1 += __shfl_xor(pel1, off, 64);
      per0 += __shfl_xor(per0, off, 64);
      per1 += __shfl_xor(per1, off, 64);
    }
    if (l15 == 0 && rv){
      elr[row*4+0] = pel0;
      elr[row*4+1] = (H == 2) ? pel1 : 0.f;
      elr[row*4+2] = per0;
      elr[row*4+3] = (H == 2) ? per1 : 0.f;
    }
  }
}

// One wave per dst node. Pass 1: flat exp-sum (no max; logits bounded, clamp 30).
// Pass 2: readlane broadcast + 16-deep gather. Optionally emits bf16 copy of out.
template<int H>
__global__ __launch_bounds__(256) void k_agg(
    const unsigned* __restrict__ fhb, const float* __restrict__ elr,
    const int* __restrict__ row_ptr, const unsigned short* __restrict__ ssrc,
    const float* __restrict__ bias, const float* __restrict__ res,
    int act, int res_from_fh,
    float* __restrict__ out, int out_ld, unsigned* __restrict__ outb, int N){
  int lane = threadIdx.x & 63, wid = threadIdx.x >> 6;
  int n = blockIdx.x*4 + wid;
  if (n >= N) return;
  int beg = row_ptr[n], end = row_ptr[n+1];
  float er0 = elr[n*4+2];
  float er1 = (H == 2) ? elr[n*4+3] : 0.f;

  // pass 1: numerators + denominator (softmax is shift-invariant; no max needed)
  float x0 = 0.f, x1 = 0.f;
  {
    int i = beg + lane;
    if (i < end){
      int s = ssrc[i];
      float2 el = *(const float2*)(elr + s*4);
      x0 = __expf(fminf(lrelu(el.x + er0), 30.f));
      if (H == 2) x1 = __expf(fminf(lrelu(el.y + er1), 30.f));
    }
  }
  float d0 = x0, d1 = x1;
  for (int i = beg + lane + 64; i < end; i += 64){
    int s = ssrc[i];
    float2 el = *(const float2*)(elr + s*4);
    d0 += __expf(fminf(lrelu(el.x + er0), 30.f));
    if (H == 2) d1 += __expf(fminf(lrelu(el.y + er1), 30.f));
  }
  #pragma unroll
  for (int off = 32; off >= 1; off >>= 1){       // add-only butterfly
    d0 += __shfl_xor(d0, off, 64);
    if (H == 2) d1 += __shfl_xor(d1, off, 64);
  }
  float rd0 = d0 > 0.f ? 1.f/d0 : 0.f;
  float rd1 = (H == 2 && d1 > 0.f) ? 1.f/d1 : 0.f;

  // pass 2: 16 gathers in flight
  float ax = 0.f, ay = 0.f;
  for (int base = beg; base < end; base += 64){
    int i = base + lane;
    int s = 0; float a0 = 0.f, a1 = 0.f;
    if (i < end){
      s = ssrc[i];
      if (base == beg){
        a0 = x0 * rd0; if (H == 2) a1 = x1 * rd1;
      } else {
        float2 el = *(const float2*)(elr + s*4);
        a0 = __expf(fminf(lrelu(el.x + er0), 30.f)) * rd0;
        if (H == 2) a1 = __expf(fminf(lrelu(el.y + er1), 30.f)) * rd1;
      }
    }
    int cnt   = min(64, end - base);
    int cnt16 = (cnt + 15) & ~15;       // pad lanes have a=0, s=0 -> contribute 0
    if (H == 2){
      for (int j0 = 0; j0 < cnt16; j0 += 16){
        unsigned w[16]; float aj[16];
        #pragma unroll
        for (int u = 0; u < 16; u++){
          int sj = __builtin_amdgcn_readlane(s, j0 + u);      // SGPR: scalar addr
          w[u] = fhb[(size_t)sj*64 + lane];                   // cols 2l,2l+1
        }
        #pragma unroll
        for (int u = 0; u < 16; u++){
          float aj0 = rl_f(a0, j0 + u);
          float aj1 = rl_f(a1, j0 + u);
          aj[u] = (lane < 32) ? aj0 : aj1;                    // head = 2l/64
        }
        #pragma unroll
        for (int u = 0; u < 16; u++){
          ax += bf2f((unsigned short)(w[u] & 0xffffu)) * aj[u];
          ay += bf2f((unsigned short)(w[u] >> 16))     * aj[u];
        }
      }
    } else {
      const unsigned short* fh16 = (const unsigned short*)fhb;
      for (int j0 = 0; j0 < cnt16; j0 += 16){
        unsigned short w[16]; float aj[16];
        #pragma unroll
        for (int u = 0; u < 16; u++){
          int sj = __builtin_amdgcn_readlane(s, j0 + u);
          w[u] = fh16[(size_t)sj*128 + lane];                 // cols 0..63
        }
        #pragma unroll
        for (int u = 0; u < 16; u++) aj[u] = rl_f(a0, j0 + u);
        #pragma unroll
        for (int u = 0; u < 16; u++) ax += bf2f(w[u]) * aj[u];
      }
    }
  }
  if (H == 2){
    int c0 = lane*2;
    float o0 = ax + bias[c0], o1 = ay + bias[c0+1];
    if (res){ o0 += res[n*128 + c0]; o1 += res[n*128 + c0+1]; }
    if (act){ o0 = o0 > 0.f ? o0 : expm1f(o0); o1 = o1 > 0.f ? o1 : expm1f(o1); }
    *(float2*)(out + n*out_ld + c0) = make_float2(o0, o1);
    if (outb) outb[(size_t)n*64 + lane] = (unsigned)f2bf(o0) | ((unsigned)f2bf(o1) << 16);
  } else {
    const unsigned short* fh16 = (const unsigned short*)fhb;
    float o = ax + bias[lane];
    if (res_from_fh) o += bf2f(fh16[(size_t)n*128 + 64 + lane]);
    out[n*out_ld + lane] = o;
  }
}

extern "C" void kernel_launch(void* const* d_in, const int* in_sizes, int n_in,
                              void* d_out, int out_size, void* d_ws, size_t ws_size,
                              hipStream_t stream) {
  const int*   feat = (const int*)  d_in[0];
  const float* fv   = (const float*)d_in[1];
  const int*   src  = (const int*)  d_in[2];
  const int*   dst  = (const int*)  d_in[3];
  const float* emb  = (const float*)d_in[4];
  const float* W0   = (const float*)d_in[5];
  const float* al0  = (const float*)d_in[6];
  const float* ar0  = (const float*)d_in[7];
  const float* b0   = (const float*)d_in[8];
  const float* W1   = (const float*)d_in[9];
  const float* al1  = (const float*)d_in[10];
  const float* ar1  = (const float*)d_in[11];
  const float* b1   = (const float*)d_in[12];
  const float* W2   = (const float*)d_in[13];
  const float* al2  = (const float*)d_in[14];
  const float* ar2  = (const float*)d_in[15];
  const float* b2   = (const float*)d_in[16];
  const float* rW2  = (const float*)d_in[17];
  const int N = in_sizes[0] / 8;   // 50000
  const int E = in_sizes[2];       // 800000

  size_t off = 0;
  auto alloc = [&](size_t bytes) -> void* {
    void* p = (char*)d_ws + off;
    off = (off + bytes + 255) & ~(size_t)255;
    return p;
  };
  unsigned short* P1 = (unsigned short*)alloc((size_t)N*128*sizeof(unsigned short)); // fhb
  float* P2     = (float*)alloc((size_t)N*128*sizeof(float));
  float* P3     = (float*)alloc((size_t)N*128*sizeof(float));
  unsigned short* hb = (unsigned short*)alloc((size_t)N*128*sizeof(unsigned short)); // h bf16
  float* elr    = (float*)alloc((size_t)N*4*sizeof(float));
  int* row_ptr  = (int*)alloc((size_t)(N+1)*sizeof(int));
  int* counts   = (int*)alloc((size_t)2*N*sizeof(int));
  int* cursor   = counts + N;
  unsigned short* ssrc = (unsigned short*)alloc((size_t)E*sizeof(unsigned short));
  int* bsum     = (int*)alloc(256*sizeof(int));
  unsigned short* Wt0 = (unsigned short*)alloc((size_t)128*64*sizeof(unsigned short));
  unsigned short* Wt1 = (unsigned short*)alloc((size_t)128*128*sizeof(unsigned short));
  unsigned short* Wt2 = (unsigned short*)alloc((size_t)128*128*sizeof(unsigned short));

  int nb1 = (N + 255) / 256;
  // CSR build
  k_zero_i32<<<(2*N + 255)/256, 256, 0, stream>>>(counts, 2*N);
  k_hist<<<(E/4 + 255)/256, 256, 0, stream>>>(dst, counts, E);
  k_scan_local<<<nb1, 256, 0, stream>>>(counts, row_ptr, bsum, N);
  k_scan_top<<<1, 256, 0, stream>>>(bsum, nb1);
  k_scan_fix<<<nb1, 256, 0, stream>>>(row_ptr, bsum, N);
  k_scatter<<<(E/4 + 255)/256, 256, 0, stream>>>(src, dst, row_ptr, cursor, ssrc, E);
  // weight transpose+bf16 prep (single dispatch)
  k_wprep_all<<<(128*64 + 2*128*128 + 255)/256, 256, 0, stream>>>(
      W0, W1, W2, rW2, Wt0, Wt1, Wt2);

  int gt = (N + 63)/64;
  int nagg = (N + 3)/4;
  // layer 0: in=64 (embed fused), H=2, no residual, elu
  k_gemm_mfma<64,2,true><<<gt, 256, 0, stream>>>(nullptr, feat, fv, emb,
      Wt0, al0, ar0, P1, elr, N);
  k_agg<2><<<nagg, 256, 0, stream>>>((unsigned*)P1, elr, row_ptr, ssrc, b0, nullptr,
                                     1, 0, P2, 128, (unsigned*)hb, N);
  // layer 1: in=128, H=2, identity residual, elu
  k_gemm_mfma<128,2,false><<<gt, 256, 0, stream>>>(hb, nullptr, nullptr, nullptr,
      Wt1, al1, ar1, P1, elr, N);
  k_agg<2><<<nagg, 256, 0, stream>>>((unsigned*)P1, elr, row_ptr, ssrc, b1, P2,
                                     1, 0, P3, 128, (unsigned*)hb, N);
  // layer 2: in=128, H=1, projected residual (fh cols 64..127 = h@resW2), no act
  k_gemm_mfma<128,1,false><<<gt, 256, 0, stream>>>(hb, nullptr, nullptr, nullptr,
      Wt2, al2, ar2, P1, elr, N);
  k_agg<1><<<nagg, 256, 0, stream>>>((unsigned*)P1, elr, row_ptr, ssrc, b2, nullptr,
                                     0, 1, (float*)d_out, 64, nullptr, N);
}

// Round 8
// 374.276 us; speedup vs baseline: 1.0105x; 1.0105x over previous
//
#include <hip/hip_runtime.h>

// GAT (3-layer) on MI355X. N=50000 nodes, E=800000 edges, D=64, H=2/2/1.
// R8: agg pass-2 = 16-deep bulk batches + 8-deep padded tail (R7's blanket
//     16-round-up wasted ~30% gathers on Poisson(16) degrees); dropped the
//     agg bf16 out-copy -- GEMM A-fragments now convert fp32->bf16 on load.

typedef __attribute__((ext_vector_type(8))) short short8;   // 8 bf16 (4 VGPRs)
typedef __attribute__((ext_vector_type(4))) float float4v;  // 4 fp32 acc

__device__ __forceinline__ float lrelu(float x){ return x >= 0.f ? x : 0.2f*x; }

__device__ __forceinline__ unsigned short f2bf(float f){   // RNE round
  unsigned int u = __float_as_uint(f);
  u += 0x7fffu + ((u >> 16) & 1u);
  return (unsigned short)(u >> 16);
}
__device__ __forceinline__ float bf2f(unsigned short u){
  return __uint_as_float((unsigned int)u << 16);
}
__device__ __forceinline__ float rl_f(float v, int l){
  return __int_as_float(__builtin_amdgcn_readlane(__float_as_int(v), l));
}

__global__ void k_zero_i32(int* __restrict__ p, int n){
  int i = blockIdx.x*blockDim.x + threadIdx.x;
  if (i < n) p[i] = 0;
}

__global__ void k_hist(const int* __restrict__ dst, int* __restrict__ counts, int E){
  int i0 = (blockIdx.x*blockDim.x + threadIdx.x)*4;
  #pragma unroll
  for (int u = 0; u < 4; u++){
    int i = i0 + u;
    if (i < E) atomicAdd(&counts[dst[i]], 1);
  }
}

__global__ void k_scan_local(const int* __restrict__ counts, int* __restrict__ row_ptr,
                             int* __restrict__ bsum, int N){
  __shared__ int s[256];
  int t = threadIdx.x, g = blockIdx.x*256 + t;
  int v = (g < N) ? counts[g] : 0;
  s[t] = v; __syncthreads();
  #pragma unroll
  for (int off = 1; off < 256; off <<= 1){
    int x = 0;
    if (t >= off) x = s[t-off];
    __syncthreads();
    s[t] += x;
    __syncthreads();
  }
  if (g < N) row_ptr[g+1] = s[t];
  if (g == 0 && t == 0) row_ptr[0] = 0;
  if (t == 255) bsum[blockIdx.x] = s[255];
}

__global__ void k_scan_top(int* __restrict__ bsum, int nb){
  __shared__ int s[256];
  int t = threadIdx.x;
  int v = (t < nb) ? bsum[t] : 0;
  s[t] = v; __syncthreads();
  #pragma unroll
  for (int off = 1; off < 256; off <<= 1){
    int x = 0;
    if (t >= off) x = s[t-off];
    __syncthreads();
    s[t] += x;
    __syncthreads();
  }
  if (t < nb) bsum[t] = s[t] - v;  // exclusive block offsets
}

__global__ void k_scan_fix(int* __restrict__ row_ptr, const int* __restrict__ bsum, int N){
  int g = blockIdx.x*256 + threadIdx.x;
  if (g < N && blockIdx.x > 0) row_ptr[g+1] += bsum[blockIdx.x];
}

// 4 edges/thread: 4 independent atomic->store chains in flight per lane.
__global__ void k_scatter(const int* __restrict__ src, const int* __restrict__ dst,
                          const int* __restrict__ row_ptr, int* __restrict__ cursor,
                          unsigned short* __restrict__ ssrc, int E){
  int i0 = (blockIdx.x*blockDim.x + threadIdx.x)*4;
  #pragma unroll
  for (int u = 0; u < 4; u++){
    int i = i0 + u;
    if (i < E){
      int d = dst[i];
      int pos = atomicAdd(&cursor[d], 1);
      ssrc[row_ptr[d] + pos] = (unsigned short)src[i];
    }
  }
}

// All three weight transposes (fp32 -> bf16, n-major) in one dispatch.
__global__ void k_wprep_all(const float* __restrict__ W0, const float* __restrict__ W1,
                            const float* __restrict__ W2, const float* __restrict__ rW2,
                            unsigned short* __restrict__ Wt0, unsigned short* __restrict__ Wt1,
                            unsigned short* __restrict__ Wt2){
  int id = blockIdx.x*256 + threadIdx.x;
  if (id < 128*64){
    int n = id/64, k = id%64;
    Wt0[n*64 + k] = f2bf(W0[k*128 + n]);
  } else if (id < 128*64 + 128*128){
    int j = id - 128*64; int n = j/128, k = j%128;
    Wt1[n*128 + k] = f2bf(W1[k*128 + n]);
  } else if (id < 128*64 + 2*128*128){
    int j = id - 128*64 - 128*128; int n = j/128, k = j%128;
    float v = (n < 64) ? W2[k*64 + n] : rW2[k*64 + (n - 64)];
    Wt2[n*128 + k] = f2bf(v);
  }
}

// MFMA GEMM: fhb[N][128](bf16 row-major) = A[N][IN] @ W(128 cols via Wt).
// AMODE: 0 = embed (A = emb[feat[row]]*fv[row], fp32->bf16), 1 = fp32 global.
// Block 256 thr = 4 waves; wave computes 16 rows x 128 cols (8 accs, IN/32 K-steps).
// Layouts (verified): A[m=lane&15][k=quad*8+j]; B[k=quad*8+j][n=lane&15];
// D: col=lane&15, row=quad*4+reg. el/er fused (16-lane butterfly per quad).
template<int IN, int H, int AMODE>
__global__ __launch_bounds__(256) void k_gemm_mfma(
    const float* __restrict__ hf,            // [N][IN] fp32 (AMODE 1)
    const int* __restrict__ feat, const float* __restrict__ fv, const float* __restrict__ emb,
    const unsigned short* __restrict__ Wt,   // [128][IN] bf16, n-major
    const float* __restrict__ al, const float* __restrict__ ar,
    unsigned short* __restrict__ fhb,        // [N][128] bf16
    float* __restrict__ elr, int N){
  constexpr int KS = IN/32;
  constexpr int LDP = IN + 8;                // +8 bf16 pad: 2-way bank aliasing = free
  __shared__ unsigned short Wt_s[128*LDP];
  const int t = threadIdx.x;
  const int lane = t & 63, wid = t >> 6;
  const int l15 = lane & 15, quad = lane >> 4;
  const int row0 = blockIdx.x*64 + wid*16;

  // stage Wt -> LDS (uint4 = 8 bf16)
  for (int id = t; id < 128*(IN/8); id += 256){
    int r = id/(IN/8), seg = id%(IN/8);
    ((uint4*)(Wt_s + r*LDP))[seg] = ((const uint4*)(Wt + (size_t)r*IN))[seg];
  }
  // A fragments (overlaps LDS staging), fp32 -> bf16 convert on load
  short8 a[KS];
  int arow = row0 + l15;
  {
    const float* ap = nullptr;
    float sc = 1.f;
    if (AMODE == 0){
      int f = 0; sc = 0.f;
      if (arow < N){ f = feat[arow]; sc = fv[arow]; }
      ap = emb + (size_t)f*64;
    } else {
      ap = (arow < N) ? hf + (size_t)arow*IN : nullptr;
    }
    #pragma unroll
    for (int s = 0; s < KS; s++){
      short8 av = short8{0,0,0,0,0,0,0,0};
      if (ap){
        const float* p = ap + s*32 + quad*8;
        float4 v0 = ((const float4*)p)[0];
        float4 v1 = ((const float4*)p)[1];
        av[0]=(short)f2bf(v0.x*sc); av[1]=(short)f2bf(v0.y*sc);
        av[2]=(short)f2bf(v0.z*sc); av[3]=(short)f2bf(v0.w*sc);
        av[4]=(short)f2bf(v1.x*sc); av[5]=(short)f2bf(v1.y*sc);
        av[6]=(short)f2bf(v1.z*sc); av[7]=(short)f2bf(v1.w*sc);
      }
      a[s] = av;
    }
  }
  __syncthreads();

  float4v acc[8];
  #pragma unroll
  for (int nt = 0; nt < 8; nt++) acc[nt] = float4v{0.f,0.f,0.f,0.f};
  #pragma unroll
  for (int nt = 0; nt < 8; nt++){
    #pragma unroll
    for (int s = 0; s < KS; s++){
      short8 b = *(const short8*)(Wt_s + (nt*16 + l15)*LDP + s*32 + quad*8);
      acc[nt] = __builtin_amdgcn_mfma_f32_16x16x32_bf16(a[s], b, acc[nt], 0, 0, 0);
    }
  }

  // al/ar at this lane's columns (col = nt*16 + l15); H==1: heads>0 are zero
  float alc[8], arc[8];
  #pragma unroll
  for (int nt = 0; nt < 8; nt++){
    bool hv = (H == 2) || (nt < 4);
    alc[nt] = hv ? al[nt*16 + l15] : 0.f;
    arc[nt] = hv ? ar[nt*16 + l15] : 0.f;
  }
  #pragma unroll
  for (int reg = 0; reg < 4; reg++){
    int row = row0 + quad*4 + reg;
    bool rv = row < N;
    if (rv){
      #pragma unroll
      for (int nt = 0; nt < 8; nt++)
        fhb[(size_t)row*128 + nt*16 + l15] = f2bf(acc[nt][reg]);
    }
    float pel0 = 0.f, per0 = 0.f, pel1 = 0.f, per1 = 0.f;
    #pragma unroll
    for (int nt = 0; nt < 4; nt++){
      pel0 += acc[nt][reg]*alc[nt];     per0 += acc[nt][reg]*arc[nt];
      pel1 += acc[nt+4][reg]*alc[nt+4]; per1 += acc[nt+4][reg]*arc[nt+4];
    }
    #pragma unroll
    for (int off = 1; off < 16; off <<= 1){   // reduce across the 16 lanes of a quad
      pel0 += __shfl_xor(pel0, off, 64);
      pel1 += __shfl_xor(pel1, off, 64);
      per0 += __shfl_xor(per0, off, 64);
      per1 += __shfl_xor(per1, off, 64);
    }
    if (l15 == 0 && rv){
      elr[row*4+0] = pel0;
      elr[row*4+1] = (H == 2) ? pel1 : 0.f;
      elr[row*4+2] = per0;
      elr[row*4+3] = (H == 2) ? per1 : 0.f;
    }
  }
}

// One wave per dst node. Pass 1: flat exp-sum (no max; logits bounded, clamp 30).
// Pass 2: readlane broadcast; 16-deep bulk + 8-deep padded tail.
template<int H>
__global__ __launch_bounds__(256) void k_agg(
    const unsigned* __restrict__ fhb, const float* __restrict__ elr,
    const int* __restrict__ row_ptr, const unsigned short* __restrict__ ssrc,
    const float* __restrict__ bias, const float* __restrict__ res,
    int act, int res_from_fh,
    float* __restrict__ out, int out_ld, int N){
  int lane = threadIdx.x & 63, wid = threadIdx.x >> 6;
  int n = blockIdx.x*4 + wid;
  if (n >= N) return;
  int beg = row_ptr[n], end = row_ptr[n+1];
  float er0 = elr[n*4+2];
  float er1 = (H == 2) ? elr[n*4+3] : 0.f;

  // pass 1: numerators + denominator (softmax is shift-invariant; no max needed)
  float x0 = 0.f, x1 = 0.f;
  {
    int i = beg + lane;
    if (i < end){
      int s = ssrc[i];
      float2 el = *(const float2*)(elr + s*4);
      x0 = __expf(fminf(lrelu(el.x + er0), 30.f));
      if (H == 2) x1 = __expf(fminf(lrelu(el.y + er1), 30.f));
    }
  }
  float d0 = x0, d1 = x1;
  for (int i = beg + lane + 64; i < end; i += 64){
    int s = ssrc[i];
    float2 el = *(const float2*)(elr + s*4);
    d0 += __expf(fminf(lrelu(el.x + er0), 30.f));
    if (H == 2) d1 += __expf(fminf(lrelu(el.y + er1), 30.f));
  }
  #pragma unroll
  for (int off = 32; off >= 1; off >>= 1){       // add-only butterfly
    d0 += __shfl_xor(d0, off, 64);
    if (H == 2) d1 += __shfl_xor(d1, off, 64);
  }
  float rd0 = d0 > 0.f ? 1.f/d0 : 0.f;
  float rd1 = (H == 2 && d1 > 0.f) ? 1.f/d1 : 0.f;

  // pass 2
  float ax = 0.f, ay = 0.f;
  for (int base = beg; base < end; base += 64){
    int i = base + lane;
    int s = 0; float a0 = 0.f, a1 = 0.f;
    if (i < end){
      s = ssrc[i];
      if (base == beg){
        a0 = x0 * rd0; if (H == 2) a1 = x1 * rd1;
      } else {
        float2 el = *(const float2*)(elr + s*4);
        a0 = __expf(fminf(lrelu(el.x + er0), 30.f)) * rd0;
        if (H == 2) a1 = __expf(fminf(lrelu(el.y + er1), 30.f)) * rd1;
      }
    }
    int cnt = min(64, end - base);
    int j0 = 0;
    if (H == 2){
      for (; j0 + 16 <= cnt; j0 += 16){            // full 16-deep batches
        unsigned w[16]; float aj[16];
        #pragma unroll
        for (int u = 0; u < 16; u++){
          int sj = __builtin_amdgcn_readlane(s, j0 + u);      // SGPR: scalar addr
          w[u] = fhb[(size_t)sj*64 + lane];                   // cols 2l,2l+1
        }
        #pragma unroll
        for (int u = 0; u < 16; u++){
          float aj0 = rl_f(a0, j0 + u);
          float aj1 = rl_f(a1, j0 + u);
          aj[u] = (lane < 32) ? aj0 : aj1;                    // head = 2l/64
        }
        #pragma unroll
        for (int u = 0; u < 16; u++){
          ax += bf2f((unsigned short)(w[u] & 0xffffu)) * aj[u];
          ay += bf2f((unsigned short)(w[u] >> 16))     * aj[u];
        }
      }
      for (; j0 < cnt; j0 += 8){                   // padded 8-deep tail
        unsigned w[8]; float aj[8];
        #pragma unroll
        for (int u = 0; u < 8; u++){
          int sj = __builtin_amdgcn_readlane(s, j0 + u);      // pad: s=0, a=0
          w[u] = fhb[(size_t)sj*64 + lane];
        }
        #pragma unroll
        for (int u = 0; u < 8; u++){
          float aj0 = rl_f(a0, j0 + u);
          float aj1 = rl_f(a1, j0 + u);
          aj[u] = (lane < 32) ? aj0 : aj1;
        }
        #pragma unroll
        for (int u = 0; u < 8; u++){
          ax += bf2f((unsigned short)(w[u] & 0xffffu)) * aj[u];
          ay += bf2f((unsigned short)(w[u] >> 16))     * aj[u];
        }
      }
    } else {
      const unsigned short* fh16 = (const unsigned short*)fhb;
      for (; j0 + 16 <= cnt; j0 += 16){
        unsigned short w[16]; float aj[16];
        #pragma unroll
        for (int u = 0; u < 16; u++){
          int sj = __builtin_amdgcn_readlane(s, j0 + u);
          w[u] = fh16[(size_t)sj*128 + lane];                 // cols 0..63
        }
        #pragma unroll
        for (int u = 0; u < 16; u++) aj[u] = rl_f(a0, j0 + u);
        #pragma unroll
        for (int u = 0; u < 16; u++) ax += bf2f(w[u]) * aj[u];
      }
      for (; j0 < cnt; j0 += 8){
        unsigned short w[8]; float aj[8];
        #pragma unroll
        for (int u = 0; u < 8; u++){
          int sj = __builtin_amdgcn_readlane(s, j0 + u);
          w[u] = fh16[(size_t)sj*128 + lane];
        }
        #pragma unroll
        for (int u = 0; u < 8; u++) aj[u] = rl_f(a0, j0 + u);
        #pragma unroll
        for (int u = 0; u < 8; u++) ax += bf2f(w[u]) * aj[u];
      }
    }
  }
  if (H == 2){
    int c0 = lane*2;
    float o0 = ax + bias[c0], o1 = ay + bias[c0+1];
    if (res){ o0 += res[n*128 + c0]; o1 += res[n*128 + c0+1]; }
    if (act){ o0 = o0 > 0.f ? o0 : expm1f(o0); o1 = o1 > 0.f ? o1 : expm1f(o1); }
    *(float2*)(out + n*out_ld + c0) = make_float2(o0, o1);
  } else {
    const unsigned short* fh16 = (const unsigned short*)fhb;
    float o = ax + bias[lane];
    if (res_from_fh) o += bf2f(fh16[(size_t)n*128 + 64 + lane]);
    out[n*out_ld + lane] = o;
  }
}

extern "C" void kernel_launch(void* const* d_in, const int* in_sizes, int n_in,
                              void* d_out, int out_size, void* d_ws, size_t ws_size,
                              hipStream_t stream) {
  const int*   feat = (const int*)  d_in[0];
  const float* fv   = (const float*)d_in[1];
  const int*   src  = (const int*)  d_in[2];
  const int*   dst  = (const int*)  d_in[3];
  const float* emb  = (const float*)d_in[4];
  const float* W0   = (const float*)d_in[5];
  const float* al0  = (const float*)d_in[6];
  const float* ar0  = (const float*)d_in[7];
  const float* b0   = (const float*)d_in[8];
  const float* W1   = (const float*)d_in[9];
  const float* al1  = (const float*)d_in[10];
  const float* ar1  = (const float*)d_in[11];
  const float* b1   = (const float*)d_in[12];
  const float* W2   = (const float*)d_in[13];
  const float* al2  = (const float*)d_in[14];
  const float* ar2  = (const float*)d_in[15];
  const float* b2   = (const float*)d_in[16];
  const float* rW2  = (const float*)d_in[17];
  const int N = in_sizes[0] / 8;   // 50000
  const int E = in_sizes[2];       // 800000

  size_t off = 0;
  auto alloc = [&](size_t bytes) -> void* {
    void* p = (char*)d_ws + off;
    off = (off + bytes + 255) & ~(size_t)255;
    return p;
  };
  unsigned short* P1 = (unsigned short*)alloc((size_t)N*128*sizeof(unsigned short)); // fhb
  float* P2     = (float*)alloc((size_t)N*128*sizeof(float));
  float* P3     = (float*)alloc((size_t)N*128*sizeof(float));
  float* elr    = (float*)alloc((size_t)N*4*sizeof(float));
  int* row_ptr  = (int*)alloc((size_t)(N+1)*sizeof(int));
  int* counts   = (int*)alloc((size_t)2*N*sizeof(int));
  int* cursor   = counts + N;
  unsigned short* ssrc = (unsigned short*)alloc((size_t)E*sizeof(unsigned short));
  int* bsum     = (int*)alloc(256*sizeof(int));
  unsigned short* Wt0 = (unsigned short*)alloc((size_t)128*64*sizeof(unsigned short));
  unsigned short* Wt1 = (unsigned short*)alloc((size_t)128*128*sizeof(unsigned short));
  unsigned short* Wt2 = (unsigned short*)alloc((size_t)128*128*sizeof(unsigned short));

  int nb1 = (N + 255) / 256;
  // CSR build
  k_zero_i32<<<(2*N + 255)/256, 256, 0, stream>>>(counts, 2*N);
  k_hist<<<(E/4 + 255)/256, 256, 0, stream>>>(dst, counts, E);
  k_scan_local<<<nb1, 256, 0, stream>>>(counts, row_ptr, bsum, N);
  k_scan_top<<<1, 256, 0, stream>>>(bsum, nb1);
  k_scan_fix<<<nb1, 256, 0, stream>>>(row_ptr, bsum, N);
  k_scatter<<<(E/4 + 255)/256, 256, 0, stream>>>(src, dst, row_ptr, cursor, ssrc, E);
  // weight transpose+bf16 prep (single dispatch)
  k_wprep_all<<<(128*64 + 2*128*128 + 255)/256, 256, 0, stream>>>(
      W0, W1, W2, rW2, Wt0, Wt1, Wt2);

  int gt = (N + 63)/64;
  int nagg = (N + 3)/4;
  // layer 0: in=64 (embed fused), H=2, no residual, elu
  k_gemm_mfma<64,2,0><<<gt, 256, 0, stream>>>(nullptr, feat, fv, emb,
      Wt0, al0, ar0, P1, elr, N);
  k_agg<2><<<nagg, 256, 0, stream>>>((unsigned*)P1, elr, row_ptr, ssrc, b0, nullptr,
                                     1, 0, P2, 128, N);
  // layer 1: in=128, H=2, identity residual, elu
  k_gemm_mfma<128,2,1><<<gt, 256, 0, stream>>>(P2, nullptr, nullptr, nullptr,
      Wt1, al1, ar1, P1, elr, N);
  k_agg<2><<<nagg, 256, 0, stream>>>((unsigned*)P1, elr, row_ptr, ssrc, b1, P2,
                                     1, 0, P3, 128, N);
  // layer 2: in=128, H=1, projected residual (fh cols 64..127 = h@resW2), no act
  k_gemm_mfma<128,1,1><<<gt, 256, 0, stream>>>(P3, nullptr, nullptr, nullptr,
      Wt2, al2, ar2, P1, elr, N);
  k_agg<1><<<nagg, 256, 0, stream>>>((unsigned*)P1, elr, row_ptr, ssrc, b2, nullptr,
                                     0, 1, (float*)d_out, 64, N);
}